// Round 1
// baseline (387.912 us; speedup 1.0000x reference)
//
#include <hip/hip_runtime.h>
#include <hip/hip_bf16.h>
#include <stdint.h>

typedef __bf16 bf16x8 __attribute__((ext_vector_type(8)));
typedef float  f32x4  __attribute__((ext_vector_type(4)));

#define MDIM 8192
#define NDIM 4096
#define KDIM 4096
#define BT   128      // tile M=N
#define BK   64       // K-step

// ---------------------------------------------------------------- helpers
__device__ __forceinline__ void lds_load16(const void* gsrc, void* ldst) {
    // async global->LDS, 16B per lane; LDS dest is wave-uniform base + lane*16
    __builtin_amdgcn_global_load_lds(
        (const __attribute__((address_space(1))) unsigned int*)gsrc,
        (__attribute__((address_space(3)))       unsigned int*)ldst,
        16, 0, 0);
}

// ---------------------------------------------------------------- x -> bf16
__global__ __launch_bounds__(256) void cvt_x(const float* __restrict__ X,
                                             __bf16* __restrict__ Xb) {
    size_t t  = (size_t)blockIdx.x * blockDim.x + threadIdx.x;  // n/8 threads
    size_t i0 = t * 8;
    float4 a = *(const float4*)(X + i0);
    float4 b = *(const float4*)(X + i0 + 4);
    bf16x8 o;
    o[0] = (__bf16)a.x; o[1] = (__bf16)a.y; o[2] = (__bf16)a.z; o[3] = (__bf16)a.w;
    o[4] = (__bf16)b.x; o[5] = (__bf16)b.y; o[6] = (__bf16)b.z; o[7] = (__bf16)b.w;
    *(bf16x8*)(Xb + i0) = o;
}

// ------------------------------------------- build Bt[c][k] = d[k]*W[c>>7][k>>7][(k-c)&127]
__global__ __launch_bounds__(256) void build_bt(const float* __restrict__ W,
                                                const float* __restrict__ d,
                                                __bf16* __restrict__ Bt) {
    int t  = blockIdx.x * blockDim.x + threadIdx.x;   // N * K/8 threads
    int c  = t >> 9;              // K/8 = 512 threads per output row
    int k0 = (t & 511) * 8;
    int i  = c  >> 7;             // k_out block
    int j  = k0 >> 7;             // k_in block (8 consecutive k never cross a 128 boundary)
    const float* wp = W + ((size_t)i * 32 + j) * 128;
    bf16x8 o;
#pragma unroll
    for (int e = 0; e < 8; ++e) {
        int k = k0 + e;
        float v = wp[(k - c) & 127] * d[k];
        o[e] = (__bf16)v;
    }
    *(bf16x8*)(Bt + (size_t)c * KDIM + k0) = o;
}

// ---------------------------------------------------------------- GEMM
// C[M][N] = A[M][K](bf16) * Bt[N][K](bf16)^T + bias ; 128x128 tile, BK=64,
// 4 waves (2x2), 4x4 16x16x32 fragments per wave (m97 structure).
__global__ __launch_bounds__(256, 2) void gemm_bc(const __bf16* __restrict__ A,
                                                  const __bf16* __restrict__ Bt,
                                                  const float* __restrict__ bias,
                                                  float* __restrict__ C) {
    __shared__ __bf16 lA[BT * BK];   // [128][64]
    __shared__ __bf16 lB[BT * BK];   // [128][64]

    // XCD-aware bijective swizzle (grid = 2048, divisible by 8)
    int nwg = gridDim.x;
    int bid = blockIdx.x;
    int cpx = nwg >> 3;
    int swz = (bid & 7) * cpx + (bid >> 3);
    int ntn = NDIM / BT;              // 32 tiles along N
    int brow = (swz / ntn) * BT;
    int bcol = (swz % ntn) * BT;

    int tid  = threadIdx.x;
    int wid  = tid >> 6;
    int lane = tid & 63;
    int wr   = wid >> 1, wc = wid & 1;        // wave grid 2x2, each 64x64 out

    f32x4 acc[4][4];
#pragma unroll
    for (int i = 0; i < 4; ++i)
#pragma unroll
        for (int j = 0; j < 4; ++j) acc[i][j] = (f32x4)0.0f;

    // staging map: thread t covers LDS bytes [t*16, t*16+16) + s*4096
    const int srow = tid >> 3;                // 0..31
    const int scol = (tid & 7) * 8;           // bf16 col offset

    const int rlo = lane & 15;                // fragment row/col within 16
    const int kg  = lane >> 4;                // k-group 0..3

    for (int kk = 0; kk < KDIM; kk += BK) {
#pragma unroll
        for (int s = 0; s < 4; ++s) {         // A tile: 128 rows x 64 cols bf16
            const __bf16* gp = A + (size_t)(brow + srow + 32 * s) * KDIM + kk + scol;
            lds_load16(gp, (char*)lA + (size_t)wid * 1024 + (size_t)s * 4096);
        }
#pragma unroll
        for (int s = 0; s < 4; ++s) {         // B tile: 128 n-rows x 64 k-cols
            const __bf16* gp = Bt + (size_t)(bcol + srow + 32 * s) * KDIM + kk + scol;
            lds_load16(gp, (char*)lB + (size_t)wid * 1024 + (size_t)s * 4096);
        }
        __syncthreads();                      // drains vmcnt before barrier

#pragma unroll
        for (int k2 = 0; k2 < 2; ++k2) {
            bf16x8 af[4], bfr[4];
#pragma unroll
            for (int i = 0; i < 4; ++i)
                af[i] = *(const bf16x8*)(lA + (wr * 64 + i * 16 + rlo) * BK + k2 * 32 + kg * 8);
#pragma unroll
            for (int j = 0; j < 4; ++j)
                bfr[j] = *(const bf16x8*)(lB + (wc * 64 + j * 16 + rlo) * BK + k2 * 32 + kg * 8);
#pragma unroll
            for (int i = 0; i < 4; ++i)
#pragma unroll
                for (int j = 0; j < 4; ++j)
                    acc[i][j] = __builtin_amdgcn_mfma_f32_16x16x32_bf16(af[i], bfr[j], acc[i][j], 0, 0, 0);
        }
        __syncthreads();
    }

    // epilogue: D mapping col=lane&15, row=(lane>>4)*4+reg  [m89]
#pragma unroll
    for (int i = 0; i < 4; ++i) {
        int rbase = brow + wr * 64 + i * 16 + kg * 4;
#pragma unroll
        for (int j = 0; j < 4; ++j) {
            int col = bcol + wc * 64 + j * 16 + rlo;
            float bs = bias[col];
#pragma unroll
            for (int r = 0; r < 4; ++r)
                C[(size_t)(rbase + r) * NDIM + col] = acc[i][j][r] + bs;
        }
    }
}

// ---------------------------------------------------------------- launch
extern "C" void kernel_launch(void* const* d_in, const int* in_sizes, int n_in,
                              void* d_out, int out_size, void* d_ws, size_t ws_size,
                              hipStream_t stream) {
    const float* x    = (const float*)d_in[0];
    const float* W    = (const float*)d_in[1];
    const float* d    = (const float*)d_in[2];
    const float* bias = (const float*)d_in[3];
    float* y = (float*)d_out;

    __bf16* Xb = (__bf16*)d_ws;                                    // 8192*4096*2 = 64 MiB
    __bf16* Bt = (__bf16*)((char*)d_ws + (size_t)MDIM * KDIM * 2); // 4096*4096*2 = 32 MiB

    cvt_x<<<(MDIM * (size_t)KDIM) / 8 / 256, 256, 0, stream>>>(x, Xb);
    build_bt<<<(NDIM * KDIM) / 8 / 256, 256, 0, stream>>>(W, d, Bt);
    gemm_bc<<<(MDIM / BT) * (NDIM / BT), 256, 0, stream>>>(Xb, Bt, bias, y);
}

// Round 3
// 283.707 us; speedup vs baseline: 1.3673x; 1.3673x over previous
//
#include <hip/hip_runtime.h>
#include <hip/hip_bf16.h>
#include <stdint.h>

typedef __bf16 bf16x8 __attribute__((ext_vector_type(8)));
typedef float  f32x4  __attribute__((ext_vector_type(4)));

#define MDIM 8192
#define NDIM 4096
#define KDIM 4096
#define BM   256
#define BN   256
#define BK   64
#define NT   (KDIM / BK)   // 64 K-tiles

// ---------------------------------------------------------------- helpers
__device__ __forceinline__ void lds_load16(const void* gsrc, void* ldst) {
    // async global->LDS, 16B/lane; LDS dest = wave-uniform base + lane*16
    __builtin_amdgcn_global_load_lds(
        (const __attribute__((address_space(1))) unsigned int*)gsrc,
        (__attribute__((address_space(3)))       unsigned int*)ldst,
        16, 0, 0);
}

// ---------------------------------------------------------------- x -> bf16
__global__ __launch_bounds__(256) void cvt_x(const float* __restrict__ X,
                                             __bf16* __restrict__ Xb) {
    size_t t  = (size_t)blockIdx.x * blockDim.x + threadIdx.x;
    size_t i0 = t * 8;
    float4 a = *(const float4*)(X + i0);
    float4 b = *(const float4*)(X + i0 + 4);
    bf16x8 o;
    o[0] = (__bf16)a.x; o[1] = (__bf16)a.y; o[2] = (__bf16)a.z; o[3] = (__bf16)a.w;
    o[4] = (__bf16)b.x; o[5] = (__bf16)b.y; o[6] = (__bf16)b.z; o[7] = (__bf16)b.w;
    *(bf16x8*)(Xb + i0) = o;
}

// ------------------------------------------- Bt[c][k] = d[k]*W[c>>7][k>>7][(k-c)&127]
__global__ __launch_bounds__(256) void build_bt(const float* __restrict__ W,
                                                const float* __restrict__ d,
                                                __bf16* __restrict__ Bt) {
    int t  = blockIdx.x * blockDim.x + threadIdx.x;
    int c  = t >> 9;
    int k0 = (t & 511) * 8;
    int i  = c  >> 7;
    int j  = k0 >> 7;
    const float* wp = W + ((size_t)i * 32 + j) * 128;
    bf16x8 o;
#pragma unroll
    for (int e = 0; e < 8; ++e) {
        int k = k0 + e;
        float v = wp[(k - c) & 127] * d[k];
        o[e] = (__bf16)v;
    }
    *(bf16x8*)(Bt + (size_t)c * KDIM + k0) = o;
}

// ---------------------------------------------------------------- GEMM
// C[M][N] = A[M][K] * Bt[N][K]^T + bias.  256x256 tile, BK=64, 8 waves (2x4),
// 8-phase-style schedule: 4 phases/K-tile, counted vmcnt(4), XOR-swizzled LDS.
//
// LDS buffer (64KB x2): region 0 = A rows 0-127, 1 = A rows 128-255,
//                       2 = B rows 0-127,  3 = B rows 128-255 (each 16KB,
//                       layout [128 rows][128B], byte-swizzle ^((row&7)<<4)).
// Stage schedule (tile t, phases 0..3): A.lo(t+1), A.hi(t+1) -> buf[~t&1];
//                                       B.lo(t+2), B.hi(t+2) -> buf[t&1].
// All overwrites land behind >=1 barrier after the region's last ds_read.
//
// vmcnt ledger at tile-t boundary (steady state): outstanding =
//   B(t+1) x4 (newest of previous boundary) + A(t+1) x4 + B(t+2) x4 = 12;
//   vmcnt(4) completes B(t+1)+A(t+1), leaves B(t+2) in flight.
// TAIL (t = NT-1): B(NT) was never staged, so outstanding = B(NT-1) x4 +
//   A(NT-1) x4 = 8 and vmcnt(4) would leave A(NT-1) IN FLIGHT (round-2 bug,
//   absmax 6.1). Drain vmcnt(0) at the last boundary only.
__global__ __launch_bounds__(512, 2) void gemm_bc(const __bf16* __restrict__ A,
                                                  const __bf16* __restrict__ Bt,
                                                  const float* __restrict__ bias,
                                                  float* __restrict__ C) {
    __shared__ __align__(16) char lds[2 * 65536];

    // T1: XCD bijective swizzle (grid = 512, 512 % 8 == 0)
    const int bid = blockIdx.x;
    const int cpx = gridDim.x >> 3;
    const int swz = (bid & 7) * cpx + (bid >> 3);
    const int ntn = NDIM / BN;                 // 16
    const int brow = (swz / ntn) * BM;
    const int bcol = (swz % ntn) * BN;

    const int tid  = threadIdx.x;
    const int wid  = tid >> 6;
    const int lane = tid & 63;
    const int wr   = wid >> 2;                 // 0..1 -> A half
    const int wc   = wid & 3;                  // 0..3 -> 64-col panel
    const int rlo  = lane & 15;
    const int kg   = lane >> 4;

    // ds_read addressing (T2 swizzle on the k-offset within each 128B row)
    const int xorK = (rlo & 7) << 4;
    const int kb0  = ((kg * 16)      ^ xorK);  // k2=0
    const int kb1  = ((64 + kg * 16) ^ xorK);  // k2=1
    const char* bufA0 = lds + wr * 16384 + rlo * 128;
    const char* bufB0 = lds + 32768 + (wc >> 1) * 16384 + ((wc & 1) * 64 + rlo) * 128;

    // staging source (pre-swizzled global col so linear LDS dest == swizzled)
    const int sRow = wid * 8 + (lane >> 3);                  // 0..63
    const int sCol = 8 * ((lane & 7) ^ ((lane >> 3) & 7));   // bf16 units

    const __bf16* Abase = A  + (size_t)brow * KDIM;
    const __bf16* Bbase = Bt + (size_t)bcol * KDIM;

    auto stageA = [&](int t_, int half, int par_) {
#pragma unroll
        for (int l = 0; l < 2; ++l) {
            const __bf16* gp = Abase + (size_t)(half * 128 + l * 64 + sRow) * KDIM
                               + t_ * 64 + sCol;
            lds_load16(gp, lds + par_ * 65536 + half * 16384 + l * 8192 + wid * 1024);
        }
    };
    auto stageB = [&](int t_, int half, int par_) {
#pragma unroll
        for (int l = 0; l < 2; ++l) {
            const __bf16* gp = Bbase + (size_t)(half * 128 + l * 64 + sRow) * KDIM
                               + t_ * 64 + sCol;
            lds_load16(gp, lds + par_ * 65536 + 32768 + half * 16384 + l * 8192 + wid * 1024);
        }
    };

    f32x4 acc[8][4];
#pragma unroll
    for (int i = 0; i < 8; ++i)
#pragma unroll
        for (int j = 0; j < 4; ++j) acc[i][j] = (f32x4)0.0f;

    // prologue: A(0),B(0) -> buf0 ; B(1) -> buf1   (12 loads/thread)
    stageA(0, 0, 0); stageA(0, 1, 0);
    stageB(0, 0, 0); stageB(0, 1, 0);
    stageB(1, 0, 1); stageB(1, 1, 1);

    bf16x8 bf[4][2];   // B fragments, live across the whole K-tile

#define PHASE(q, STAGE_STMT)                                                        \
    {                                                                               \
        bf16x8 a00 = *(const bf16x8*)(bufA + (q) * 4096 +    0 + kb0);              \
        bf16x8 a01 = *(const bf16x8*)(bufA + (q) * 4096 +    0 + kb1);              \
        bf16x8 a10 = *(const bf16x8*)(bufA + (q) * 4096 + 2048 + kb0);              \
        bf16x8 a11 = *(const bf16x8*)(bufA + (q) * 4096 + 2048 + kb1);              \
        STAGE_STMT;                                                                 \
        __builtin_amdgcn_s_barrier();                                               \
        asm volatile("s_waitcnt lgkmcnt(0)" ::: "memory");                          \
        __builtin_amdgcn_s_setprio(1);                                              \
        _Pragma("unroll")                                                           \
        for (int j = 0; j < 4; ++j) {                                               \
            acc[(q)*2+0][j] = __builtin_amdgcn_mfma_f32_16x16x32_bf16(a00, bf[j][0], acc[(q)*2+0][j], 0, 0, 0); \
            acc[(q)*2+0][j] = __builtin_amdgcn_mfma_f32_16x16x32_bf16(a01, bf[j][1], acc[(q)*2+0][j], 0, 0, 0); \
            acc[(q)*2+1][j] = __builtin_amdgcn_mfma_f32_16x16x32_bf16(a10, bf[j][0], acc[(q)*2+1][j], 0, 0, 0); \
            acc[(q)*2+1][j] = __builtin_amdgcn_mfma_f32_16x16x32_bf16(a11, bf[j][1], acc[(q)*2+1][j], 0, 0, 0); \
        }                                                                           \
        __builtin_amdgcn_s_setprio(0);                                              \
    }

    for (int t = 0; t < NT; ++t) {
        const int par = t & 1;
        const char* bufA = bufA0 + par * 65536;
        const char* bufB = bufB0 + par * 65536;

        // tile boundary: keep newest 4 loads (B(t+2) halves) in flight —
        // except at the LAST tile, where B(NT) was never staged and the
        // newest 4 are A(NT-1) itself: drain fully there.
        if (t < NT - 1) {
            asm volatile("s_waitcnt vmcnt(4)" ::: "memory");
        } else {
            asm volatile("s_waitcnt vmcnt(0)" ::: "memory");
        }
        __builtin_amdgcn_s_barrier();

        // phase 0: read all B frags + A quad0 ; stage A.lo(t+1)
#pragma unroll
        for (int j = 0; j < 4; ++j) {
            bf[j][0] = *(const bf16x8*)(bufB + j * 2048 + kb0);
            bf[j][1] = *(const bf16x8*)(bufB + j * 2048 + kb1);
        }
        PHASE(0, { if (t + 1 < NT) stageA(t + 1, 0, 1 - par); });
        // phase 1: A quad1 ; stage A.hi(t+1)
        PHASE(1, { if (t + 1 < NT) stageA(t + 1, 1, 1 - par); });
        // phase 2: A quad2 ; stage B.lo(t+2)
        PHASE(2, { if (t + 2 < NT) stageB(t + 2, 0, par); });
        // phase 3: A quad3 ; stage B.hi(t+2)
        PHASE(3, { if (t + 2 < NT) stageB(t + 2, 1, par); });
    }
#undef PHASE

    // epilogue: D layout col=lane&15, row=(lane>>4)*4+reg  [m89]
#pragma unroll
    for (int j = 0; j < 4; ++j) {
        const int col = bcol + wc * 64 + j * 16 + rlo;
        const float bs = bias[col];
#pragma unroll
        for (int i = 0; i < 8; ++i) {
            const int row = brow + wr * 128 + i * 16 + kg * 4;
#pragma unroll
            for (int r = 0; r < 4; ++r)
                C[(size_t)(row + r) * NDIM + col] = acc[i][j][r] + bs;
        }
    }
}

// ---------------------------------------------------------------- launch
extern "C" void kernel_launch(void* const* d_in, const int* in_sizes, int n_in,
                              void* d_out, int out_size, void* d_ws, size_t ws_size,
                              hipStream_t stream) {
    const float* x    = (const float*)d_in[0];
    const float* W    = (const float*)d_in[1];
    const float* d    = (const float*)d_in[2];
    const float* bias = (const float*)d_in[3];
    float* y = (float*)d_out;

    __bf16* Xb = (__bf16*)d_ws;                                    // 64 MiB
    __bf16* Bt = (__bf16*)((char*)d_ws + (size_t)MDIM * KDIM * 2); // 32 MiB

    cvt_x<<<(MDIM * (size_t)KDIM) / 8 / 256, 256, 0, stream>>>(x, Xb);
    build_bt<<<(NDIM * KDIM) / 8 / 256, 256, 0, stream>>>(W, d, Bt);
    gemm_bc<<<(MDIM / BM) * (NDIM / BN), 512, 0, stream>>>(Xb, Bt, bias, y);
}